// Round 1
// baseline (946.975 us; speedup 1.0000x reference)
//
#include <hip/hip_runtime.h>

#define IMG_W 1024
#define SLICE 1048576   // 1024*1024, one (n,c) plane
#define INF_F __builtin_huge_valf()

// ---- DPP wave64 sum: canonical GCN row_shr/row_bcast chain, total lands in lane 63.
template <int CTRL>
__device__ __forceinline__ float dpp_add_step(float x) {
    int m = __builtin_amdgcn_update_dpp(0, __builtin_bit_cast(int, x), CTRL, 0xf, 0xf, true);
    return x + __builtin_bit_cast(float, m);
}
__device__ __forceinline__ float wave_sum63(float x) {
    x = dpp_add_step<0x111>(x);  // row_shr:1
    x = dpp_add_step<0x112>(x);  // row_shr:2
    x = dpp_add_step<0x114>(x);  // row_shr:4
    x = dpp_add_step<0x118>(x);  // row_shr:8
    x = dpp_add_step<0x142>(x);  // row_bcast:15
    x = dpp_add_step<0x143>(x);  // row_bcast:31
    return x;                    // lane 63 holds the wave total
}

typedef const float __attribute__((address_space(1))) gfloat;
typedef float __attribute__((address_space(3))) sfloat;

// ============================================================================
// L0 (single pass): all 12 planes folded in-WG; per-lane scalar accumulators
// acc[di][dy] live across the plane loop so the wave-reduce is paid once per
// candidate, not once per (candidate,plane).  Writes FINAL summed cost.
// Grid (tx=32, byo=8, dxq=4), 256 threads = 4 waves; wave w owns by = byo*4+w.
// WG owns di in [dxq*4, dxq*4+ndi), ndi = 4,4,4,5.
// Target tile: 20 block-col slices of target block-row tx (80 KB), staged per
// plane via async global_load_lds; ref blocks register-resident per plane,
// reused across all 17 dy.
// cost[(bx*32+by)*289 + di*17 + (dy+8)] = sum over 12 planes (valid combos only).
// ============================================================================
__global__ __launch_bounds__(256, 2) void hbma_l0(const float* __restrict__ ref,
                                                  const float* __restrict__ tgt,
                                                  float* __restrict__ cost) {
    const int tx  = blockIdx.x;   // target block row 0..31
    const int byo = blockIdx.y;   // by octet 0..7  (4 by values)
    const int dxq = blockIdx.z;   // dx quarter 0..3
    const int di0 = dxq * 4;
    const int ndi = (dxq == 3) ? 5 : 4;
    const int t = threadIdx.x, lane = t & 63, w = t >> 6;
    const int by = byo * 4 + w;
    const int prow = lane >> 3, pcol = (lane & 7) << 2;
    const int ty0 = byo * 4 - 8;  // slice jj = ty - ty0 in [0,20)

    __shared__ float tile[20 * 1024];   // 80 KB -> 2 WGs/CU

    float acc[5][17];
    #pragma unroll
    for (int d = 0; d < 5; ++d)
        #pragma unroll
        for (int y = 0; y < 17; ++y) acc[d][y] = 0.f;

    bool rvalid[5]; int bxv[5];
    #pragma unroll
    for (int d = 0; d < 5; ++d) {
        const int bx = tx - (di0 + d - 8);
        bxv[d] = bx;
        rvalid[d] = (d < ndi) && ((unsigned)bx < 32u);
    }

    const int srr = t >> 3, scc = (t & 7) << 2;   // staging footprint: row, col4

    for (int plane = 0; plane < 12; ++plane) {
        const float* tgt_p = tgt + (size_t)plane * SLICE;
        const float* ref_p = ref + (size_t)plane * SLICE;

        __syncthreads();   // previous plane's tile fully consumed
        // async stage: slice i holds tgt block (tx, ty0+i) as [32 rows][32 cols].
        // LDS dest is linear (i*256+t)*16 B = wave-uniform base + lane*16.  [m97 pattern]
        #pragma unroll
        for (int i = 0; i < 20; ++i) {
            const int ty = ty0 + i;
            if ((unsigned)ty < 32u) {   // uniform per iteration
                __builtin_amdgcn_global_load_lds(
                    (gfloat*)(tgt_p + (size_t)(tx * 32 + srr) * IMG_W + ty * 32 + scc),
                    (sfloat*)&tile[(i * 256 + t) * 4], 16, 0, 0);
            }
        }
        __syncthreads();   // compiler drains vmcnt before s_barrier

        // ref blocks for this plane: register-resident, reused across all 17 dy
        float4 rf[5][4];
        #pragma unroll
        for (int d = 0; d < 5; ++d)
            if (rvalid[d]) {
                const float* rb = ref_p + (size_t)(bxv[d] * 32 + prow) * IMG_W + by * 32 + pcol;
                #pragma unroll
                for (int i = 0; i < 4; ++i)
                    rf[d][i] = *(const float4*)(rb + (size_t)i * 8 * IMG_W);
            }

        #pragma unroll
        for (int yi = 0; yi < 17; ++yi) {
            const int ty = by + yi - 8;
            if ((unsigned)ty < 32u) {          // wave-uniform
                const int tb = (ty - ty0) * 1024 + prow * 32 + pcol;
                float4 tv[4];
                #pragma unroll
                for (int i = 0; i < 4; ++i) tv[i] = *(const float4*)&tile[tb + i * 256];
                #pragma unroll
                for (int d = 0; d < 5; ++d)
                    if (rvalid[d]) {           // wave-uniform
                        float4 a = {0.f, 0.f, 0.f, 0.f};
                        #pragma unroll
                        for (int i = 0; i < 4; ++i) {
                            a.x += __builtin_fabsf(rf[d][i].x - tv[i].x);
                            a.y += __builtin_fabsf(rf[d][i].y - tv[i].y);
                            a.z += __builtin_fabsf(rf[d][i].z - tv[i].z);
                            a.w += __builtin_fabsf(rf[d][i].w - tv[i].w);
                        }
                        acc[d][yi] += (a.x + a.y) + (a.z + a.w);
                    }
            }
        }
    }

    // epilogue: one wave-reduce per candidate (amortized over 12 planes)
    #pragma unroll
    for (int d = 0; d < 5; ++d)
        if (rvalid[d]) {
            #pragma unroll
            for (int yi = 0; yi < 17; ++yi) {
                const int ty = by + yi - 8;
                if ((unsigned)ty < 32u) {
                    const float s = wave_sum63(acc[d][yi]);
                    if (lane == 63)
                        cost[((size_t)bxv[d] * 32 + by) * 289 + (size_t)(di0 + d) * 17 + yi] = s;
                }
            }
        }
}

// ============================================================================
// L1: fused parent-argmin prologue (replaces the old phase-2 kernel) + the
// proven child-search body.  One WG per PARENT -> 4 children share the
// identical 81-candidate window; fuses MV write + predicted-frame gather.
// ============================================================================
__global__ __launch_bounds__(256) void hbma_l1(const float* __restrict__ ref,
                                               const float* __restrict__ tgt,
                                               const float* __restrict__ cost,
                                               float* __restrict__ out) {
    const int pby = blockIdx.x;  // 0..31
    const int pbx = blockIdx.y;  // 0..31
    const int t = threadIdx.x;
    const int lane = t & 63, w = t >> 6;

    __shared__ float partials[4][81][4];
    __shared__ int2 sbest[4];
    __shared__ float pm_c[4];
    __shared__ int pm_k[4];

    // ---- parent argmin over 289 candidates (first-min in lex (dx,dy) order)
    float bc = INF_F; int bk = 1 << 30;
    {
        const float* crow = cost + ((size_t)pbx * 32 + pby) * 289;
        for (int k = t; k < 289; k += 256) {
            const int dx = k / 17 - 8, dy = k % 17 - 8;
            if ((unsigned)(pbx + dx) < 32u && (unsigned)(pby + dy) < 32u) {
                const float c = crow[k];
                if (c < bc) { bc = c; bk = k; }
            }
        }
        #pragma unroll
        for (int o = 32; o > 0; o >>= 1) {
            const float oc = __shfl_down(bc, o, 64);
            const int   ok = __shfl_down(bk, o, 64);
            if (oc < bc || (oc == bc && ok < bk)) { bc = oc; bk = ok; }
        }
        if (lane == 0) { pm_c[w] = bc; pm_k[w] = bk; }
        __syncthreads();
        bc = pm_c[0]; bk = pm_k[0];
        #pragma unroll
        for (int j = 1; j < 4; ++j) {
            const float oc = pm_c[j]; const int ok = pm_k[j];
            if (oc < bc || (oc == bc && ok < bk)) { bc = oc; bk = ok; }
        }
    }
    const int cx = 2 * (pbx + bk / 17 - 8);
    const int cy = 2 * (pby + bk % 17 - 8);

    // thread's 12-px footprint of a 16x16x12 child block (3 float4s)
    int off[3];
    #pragma unroll
    for (int i = 0; i < 3; ++i) {
        const int e4 = t + 256 * i;
        const int nc = e4 >> 6;
        const int ww = e4 & 63;
        off[i] = nc * SLICE + (ww >> 2) * IMG_W + ((ww & 3) << 2);
    }
    int cbase[4];
    float4 rf[4][3];
    #pragma unroll
    for (int c = 0; c < 4; ++c) {
        const int bx = 2 * pbx + (c >> 1), by = 2 * pby + (c & 1);
        cbase[c] = (bx * 16) * IMG_W + by * 16;
        #pragma unroll
        for (int i = 0; i < 3; ++i)
            rf[c][i] = *(const float4*)(ref + cbase[c] + off[i]);
    }

    for (int k = 0; k < 81; ++k) {
        const int tx = cx + k / 9 - 4;
        const int ty = cy + k % 9 - 4;
        if ((unsigned)tx < 64u && (unsigned)ty < 64u) {   // WG-uniform
            const float* tb = tgt + (tx * 16) * IMG_W + ty * 16;
            float4 tv[3];
            #pragma unroll
            for (int i = 0; i < 3; ++i) tv[i] = *(const float4*)(tb + off[i]);
            #pragma unroll
            for (int c = 0; c < 4; ++c) {
                float4 a = {0.f, 0.f, 0.f, 0.f};
                #pragma unroll
                for (int i = 0; i < 3; ++i) {
                    a.x += __builtin_fabsf(rf[c][i].x - tv[i].x);
                    a.y += __builtin_fabsf(rf[c][i].y - tv[i].y);
                    a.z += __builtin_fabsf(rf[c][i].z - tv[i].z);
                    a.w += __builtin_fabsf(rf[c][i].w - tv[i].w);
                }
                const float s = wave_sum63((a.x + a.y) + (a.z + a.w));
                if (lane == 63) partials[c][k][w] = s;
            }
        } else if (lane == 63) {
            #pragma unroll
            for (int c = 0; c < 4; ++c) partials[c][k][w] = INF_F;
        }
    }
    __syncthreads();

    // wave w finds argmin for child w
    {
        const int c = w;
        float cbc = INF_F; int cbk = 1 << 30;
        for (int k = lane; k < 81; k += 64) {
            const float4 p4 = *(const float4*)&partials[c][k][0];
            const float cst = (p4.x + p4.y) + (p4.z + p4.w);
            if (cst < cbc) { cbc = cst; cbk = k; }
        }
        #pragma unroll
        for (int o = 32; o > 0; o >>= 1) {
            const float oc = __shfl_down(cbc, o, 64);
            const int   ok = __shfl_down(cbk, o, 64);
            if (oc < cbc || (oc == cbc && ok < cbk)) { cbc = oc; cbk = ok; }
        }
        if (lane == 0) sbest[c] = make_int2(cx + cbk / 9 - 4, cy + cbk % 9 - 4);
    }
    __syncthreads();

    // motion vectors: out[0..32767] as [N=4][2][64][64] (same for all n)
    if (t < 32) {
        const int c = t >> 3, n = (t >> 1) & 3, ch = t & 1;
        const int bx = 2 * pbx + (c >> 1), by = 2 * pby + (c & 1);
        const int2 fb = sbest[c];
        out[((n * 2 + ch) * 64 + bx) * 64 + by] = (ch == 0) ? (float)(fb.x - bx) : (float)(fb.y - by);
    }

    // predicted frame gather for all 4 children
    float* pred = out + 32768;
    #pragma unroll
    for (int c = 0; c < 4; ++c) {
        const int2 fb = sbest[c];
        const float* sb = tgt + (fb.x * 16) * IMG_W + fb.y * 16;
        float* db = pred + cbase[c];
        #pragma unroll
        for (int i = 0; i < 3; ++i)
            *(float4*)(db + off[i]) = *(const float4*)(sb + off[i]);
    }
}

extern "C" void kernel_launch(void* const* d_in, const int* in_sizes, int n_in,
                              void* d_out, int out_size, void* d_ws, size_t ws_size,
                              hipStream_t stream) {
    const float* ref = (const float*)d_in[0];
    const float* tgt = (const float*)d_in[1];
    float* out = (float*)d_out;

    float* cost = (float*)d_ws;   // 1024 blocks * 289 candidates * 4 B = 1.18 MB

    hbma_l0<<<dim3(32, 8, 4), 256, 0, stream>>>(ref, tgt, cost);
    hbma_l1<<<dim3(32, 32), 256, 0, stream>>>(ref, tgt, cost, out);
}

// Round 2
// 604.747 us; speedup vs baseline: 1.5659x; 1.5659x over previous
//
#include <hip/hip_runtime.h>

#define IMG_W 1024
#define SLICE 1048576   // 1024*1024, one (n,c) plane
#define INF_F __builtin_huge_valf()

// ---- DPP wave64 sum: canonical GCN row_shr/row_bcast chain, total lands in lane 63.
template <int CTRL>
__device__ __forceinline__ float dpp_add_step(float x) {
    int m = __builtin_amdgcn_update_dpp(0, __builtin_bit_cast(int, x), CTRL, 0xf, 0xf, true);
    return x + __builtin_bit_cast(float, m);
}
__device__ __forceinline__ float wave_sum63(float x) {
    x = dpp_add_step<0x111>(x);  // row_shr:1
    x = dpp_add_step<0x112>(x);  // row_shr:2
    x = dpp_add_step<0x114>(x);  // row_shr:4
    x = dpp_add_step<0x118>(x);  // row_shr:8
    x = dpp_add_step<0x142>(x);  // row_bcast:15
    x = dpp_add_step<0x143>(x);  // row_bcast:31
    return x;                    // lane 63 holds the wave total
}

typedef const float __attribute__((address_space(1))) gfloat;
typedef float __attribute__((address_space(3))) sfloat;

// ============================================================================
// L0: plane-fold with SMALL per-wave candidate tile (2 di x 17 dy = 34 regs of
// acc + 32 regs rf ≈ 105 VGPR live -> no spill under the 128 cap; round-1's
// 5-di variant spilled 441 MB to scratch).  Wave-reduce amortized over 12
// planes.  Writes FINAL summed cost.
// Grid (tx=32, byo=8, dxp=9), 256 threads = 4 waves; wave w owns by = byo*4+w.
// WG owns di in {dxp*2, dxp*2+1} (dxp=8 -> 1 di).
// Natural dispatch order keeps all same-tx WGs on one XCD (id % 8 == tx % 8)
// so the 1.5 MB tgt block-row working set stays L2-resident.
// ============================================================================
__global__ __launch_bounds__(256, 2) void hbma_l0(const float* __restrict__ ref,
                                                  const float* __restrict__ tgt,
                                                  float* __restrict__ cost) {
    const int tx  = blockIdx.x;   // target block row 0..31
    const int byo = blockIdx.y;   // by octet 0..7  (4 by values)
    const int dxp = blockIdx.z;   // di pair 0..8
    const int di0 = dxp * 2;
    const int ndi = (di0 + 1 < 17) ? 2 : 1;
    const int t = threadIdx.x, lane = t & 63, w = t >> 6;
    const int by = byo * 4 + w;
    const int prow = lane >> 3, pcol = (lane & 7) << 2;
    const int ty0 = byo * 4 - 8;  // slice jj = ty - ty0 in [0,20)

    bool rvalid[2]; int bxv[2];
    #pragma unroll
    for (int d = 0; d < 2; ++d) {
        const int bx = tx - (di0 + d - 8);
        bxv[d] = bx;
        rvalid[d] = (d < ndi) && ((unsigned)bx < 32u);
    }
    if (!rvalid[0] && !rvalid[1]) return;   // WG-uniform early-out (clipped dx)

    __shared__ float tile[20 * 1024];   // 80 KB -> 2 WGs/CU

    float acc[2][17];
    #pragma unroll
    for (int d = 0; d < 2; ++d)
        #pragma unroll
        for (int y = 0; y < 17; ++y) acc[d][y] = 0.f;

    const int srr = t >> 3, scc = (t & 7) << 2;   // staging footprint: row, col4

    for (int plane = 0; plane < 12; ++plane) {
        const float* tgt_p = tgt + (size_t)plane * SLICE;
        const float* ref_p = ref + (size_t)plane * SLICE;

        __syncthreads();   // previous plane's tile fully consumed
        // async stage: slice i holds tgt block (tx, ty0+i) as [32 rows][32 cols].
        // LDS dest linear (i*256+t)*16 B = wave-uniform base + lane*16.
        #pragma unroll
        for (int i = 0; i < 20; ++i) {
            const int ty = ty0 + i;
            if ((unsigned)ty < 32u) {   // uniform per iteration
                __builtin_amdgcn_global_load_lds(
                    (gfloat*)(tgt_p + (size_t)(tx * 32 + srr) * IMG_W + ty * 32 + scc),
                    (sfloat*)&tile[(i * 256 + t) * 4], 16, 0, 0);
            }
        }
        __syncthreads();   // compiler drains vmcnt before s_barrier

        // ref blocks for this plane: register-resident, reused across all 17 dy
        float4 rf[2][4];
        #pragma unroll
        for (int d = 0; d < 2; ++d)
            if (rvalid[d]) {
                const float* rb = ref_p + (size_t)(bxv[d] * 32 + prow) * IMG_W + by * 32 + pcol;
                #pragma unroll
                for (int i = 0; i < 4; ++i)
                    rf[d][i] = *(const float4*)(rb + (size_t)i * 8 * IMG_W);
            }

        #pragma unroll
        for (int yi = 0; yi < 17; ++yi) {
            const int ty = by + yi - 8;
            if ((unsigned)ty < 32u) {          // wave-uniform
                const int tb = (ty - ty0) * 1024 + prow * 32 + pcol;
                float4 tv[4];
                #pragma unroll
                for (int i = 0; i < 4; ++i) tv[i] = *(const float4*)&tile[tb + i * 256];
                #pragma unroll
                for (int d = 0; d < 2; ++d)
                    if (rvalid[d]) {           // wave-uniform
                        float4 a = {0.f, 0.f, 0.f, 0.f};
                        #pragma unroll
                        for (int i = 0; i < 4; ++i) {
                            a.x += __builtin_fabsf(rf[d][i].x - tv[i].x);
                            a.y += __builtin_fabsf(rf[d][i].y - tv[i].y);
                            a.z += __builtin_fabsf(rf[d][i].z - tv[i].z);
                            a.w += __builtin_fabsf(rf[d][i].w - tv[i].w);
                        }
                        acc[d][yi] += (a.x + a.y) + (a.z + a.w);
                    }
            }
        }
    }

    // epilogue: one wave-reduce per candidate (amortized over 12 planes)
    #pragma unroll
    for (int d = 0; d < 2; ++d)
        if (rvalid[d]) {
            #pragma unroll
            for (int yi = 0; yi < 17; ++yi) {
                const int ty = by + yi - 8;
                if ((unsigned)ty < 32u) {
                    const float s = wave_sum63(acc[d][yi]);
                    if (lane == 63)
                        cost[((size_t)bxv[d] * 32 + by) * 289 + (size_t)(di0 + d) * 17 + yi] = s;
                }
            }
        }
}

// ============================================================================
// L1: fused parent-argmin prologue + child search.  One WG per PARENT; 4
// children share the 81-candidate window.  New this round:
//  - k-loop software pipeline (ping-pong tvA/tvB, issue k+1 loads before
//    computing k -> L3 latency hidden under ~160 VALU instrs)
//  - XCD-chunked parent swizzle (each XCD owns 4 contiguous pbx rows)
// ============================================================================
__global__ __launch_bounds__(256) void hbma_l1(const float* __restrict__ ref,
                                               const float* __restrict__ tgt,
                                               const float* __restrict__ cost,
                                               float* __restrict__ out) {
    // XCD-chunked swizzle: pid -> (pbx, pby), 8 chunks of 4 pbx-rows each.
    const int pid = blockIdx.y * 32 + blockIdx.x;
    const int pbx = ((pid & 7) << 2) + ((pid >> 3) >> 5);
    const int pby = (pid >> 3) & 31;
    const int t = threadIdx.x;
    const int lane = t & 63, w = t >> 6;

    __shared__ float partials[4][81][4];
    __shared__ int2 sbest[4];
    __shared__ float pm_c[4];
    __shared__ int pm_k[4];

    // ---- parent argmin over 289 candidates (first-min in lex (dx,dy) order)
    float bc = INF_F; int bk = 1 << 30;
    {
        const float* crow = cost + ((size_t)pbx * 32 + pby) * 289;
        for (int k = t; k < 289; k += 256) {
            const int dx = k / 17 - 8, dy = k % 17 - 8;
            if ((unsigned)(pbx + dx) < 32u && (unsigned)(pby + dy) < 32u) {
                const float c = crow[k];
                if (c < bc) { bc = c; bk = k; }
            }
        }
        #pragma unroll
        for (int o = 32; o > 0; o >>= 1) {
            const float oc = __shfl_down(bc, o, 64);
            const int   ok = __shfl_down(bk, o, 64);
            if (oc < bc || (oc == bc && ok < bk)) { bc = oc; bk = ok; }
        }
        if (lane == 0) { pm_c[w] = bc; pm_k[w] = bk; }
        __syncthreads();
        bc = pm_c[0]; bk = pm_k[0];
        #pragma unroll
        for (int j = 1; j < 4; ++j) {
            const float oc = pm_c[j]; const int ok = pm_k[j];
            if (oc < bc || (oc == bc && ok < bk)) { bc = oc; bk = ok; }
        }
    }
    const int cx = 2 * (pbx + bk / 17 - 8);
    const int cy = 2 * (pby + bk % 17 - 8);

    // thread's 12-px footprint of a 16x16x12 child block (3 float4s)
    int off[3];
    #pragma unroll
    for (int i = 0; i < 3; ++i) {
        const int e4 = t + 256 * i;
        const int nc = e4 >> 6;
        const int ww = e4 & 63;
        off[i] = nc * SLICE + (ww >> 2) * IMG_W + ((ww & 3) << 2);
    }
    int cbase[4];
    float4 rf[4][3];
    #pragma unroll
    for (int c = 0; c < 4; ++c) {
        const int bx = 2 * pbx + (c >> 1), by = 2 * pby + (c & 1);
        cbase[c] = (bx * 16) * IMG_W + by * 16;
        #pragma unroll
        for (int i = 0; i < 3; ++i)
            rf[c][i] = *(const float4*)(ref + cbase[c] + off[i]);
    }

    // ---- pipelined candidate loop
    auto issue = [&](int k, float4 (&tv)[3]) -> bool {
        const int ttx = cx + k / 9 - 4;
        const int tty = cy + k % 9 - 4;
        const bool valid = ((unsigned)ttx < 64u) && ((unsigned)tty < 64u);
        if (valid) {   // WG-uniform
            const float* tb = tgt + (ttx * 16) * IMG_W + tty * 16;
            #pragma unroll
            for (int i = 0; i < 3; ++i) tv[i] = *(const float4*)(tb + off[i]);
        }
        return valid;
    };
    auto compute = [&](int k, const float4 (&tv)[3], bool valid) {
        if (k >= 81) return;           // WG-uniform
        if (valid) {                   // WG-uniform
            #pragma unroll
            for (int c = 0; c < 4; ++c) {
                float4 a = {0.f, 0.f, 0.f, 0.f};
                #pragma unroll
                for (int i = 0; i < 3; ++i) {
                    a.x += __builtin_fabsf(rf[c][i].x - tv[i].x);
                    a.y += __builtin_fabsf(rf[c][i].y - tv[i].y);
                    a.z += __builtin_fabsf(rf[c][i].z - tv[i].z);
                    a.w += __builtin_fabsf(rf[c][i].w - tv[i].w);
                }
                const float s = wave_sum63((a.x + a.y) + (a.z + a.w));
                if (lane == 63) partials[c][k][w] = s;
            }
        } else if (lane == 63) {
            #pragma unroll
            for (int c = 0; c < 4; ++c) partials[c][k][w] = INF_F;
        }
    };

    float4 tvA[3], tvB[3];
    bool vA = issue(0, tvA);
    for (int k = 0; k < 81; k += 2) {
        const bool vB = (k + 1 < 81) && issue(k + 1, tvB);
        compute(k, tvA, vA);
        const bool vA2 = (k + 2 < 81) && issue(k + 2, tvA);
        compute(k + 1, tvB, vB);
        vA = vA2;
    }
    __syncthreads();

    // wave w finds argmin for child w
    {
        const int c = w;
        float cbc = INF_F; int cbk = 1 << 30;
        for (int k = lane; k < 81; k += 64) {
            const float4 p4 = *(const float4*)&partials[c][k][0];
            const float cst = (p4.x + p4.y) + (p4.z + p4.w);
            if (cst < cbc) { cbc = cst; cbk = k; }
        }
        #pragma unroll
        for (int o = 32; o > 0; o >>= 1) {
            const float oc = __shfl_down(cbc, o, 64);
            const int   ok = __shfl_down(cbk, o, 64);
            if (oc < cbc || (oc == cbc && ok < cbk)) { cbc = oc; cbk = ok; }
        }
        if (lane == 0) sbest[c] = make_int2(cx + cbk / 9 - 4, cy + cbk % 9 - 4);
    }
    __syncthreads();

    // motion vectors: out[0..32767] as [N=4][2][64][64] (same for all n)
    if (t < 32) {
        const int c = t >> 3, n = (t >> 1) & 3, ch = t & 1;
        const int bx = 2 * pbx + (c >> 1), by = 2 * pby + (c & 1);
        const int2 fb = sbest[c];
        out[((n * 2 + ch) * 64 + bx) * 64 + by] = (ch == 0) ? (float)(fb.x - bx) : (float)(fb.y - by);
    }

    // predicted frame gather for all 4 children
    float* pred = out + 32768;
    #pragma unroll
    for (int c = 0; c < 4; ++c) {
        const int2 fb = sbest[c];
        const float* sb = tgt + (fb.x * 16) * IMG_W + fb.y * 16;
        float* db = pred + cbase[c];
        #pragma unroll
        for (int i = 0; i < 3; ++i)
            *(float4*)(db + off[i]) = *(const float4*)(sb + off[i]);
    }
}

extern "C" void kernel_launch(void* const* d_in, const int* in_sizes, int n_in,
                              void* d_out, int out_size, void* d_ws, size_t ws_size,
                              hipStream_t stream) {
    const float* ref = (const float*)d_in[0];
    const float* tgt = (const float*)d_in[1];
    float* out = (float*)d_out;

    float* cost = (float*)d_ws;   // 1024 blocks * 289 candidates * 4 B = 1.18 MB

    hbma_l0<<<dim3(32, 8, 9), 256, 0, stream>>>(ref, tgt, cost);
    hbma_l1<<<dim3(32, 32), 256, 0, stream>>>(ref, tgt, cost, out);
}